// Round 1
// baseline (119.058 us; speedup 1.0000x reference)
//
#include <hip/hip_runtime.h>

// 3-NN inverse-distance-weighted upsampling.
// B=2, N=16384, S=4096 (fixed by setup_inputs).
// Distances & weights in fp64 so neighbor ordering matches the numpy
// reference exactly (fp32 ordering risks 3rd/4th-neighbor tie flips
// which blow past the absmax threshold).

constexpr int S_SPARSE = 4096;
constexpr int NSPLIT   = 4;            // S-dimension split per dense point
constexpr int PPB      = 64;           // dense points per block
constexpr int THREADS  = PPB * NSPLIT; // 256

__global__ __launch_bounds__(THREADS)
void upsample_knn3(const float* __restrict__ xyz,
                   const float* __restrict__ sxyz,
                   const float* __restrict__ sflow,
                   float* __restrict__ out,
                   int N)
{
    __shared__ float4 sp[S_SPARSE];          // 64 KiB: (x,y,z,pad) per sparse pt
    __shared__ double md[PPB][NSPLIT][3];    // 6 KiB merge scratch (dists)
    __shared__ int    mi[PPB][NSPLIT][3];    // 3 KiB merge scratch (indices)

    const int b     = blockIdx.y;
    const int lp    = threadIdx.x >> 2;        // local point 0..63
    const int split = threadIdx.x & (NSPLIT - 1);
    const int pt    = blockIdx.x * PPB + lp;

    // ---- stage sparse coords (SoA global -> AoS float4 LDS) ----
    {
        const float* sx = sxyz + (size_t)b * 3 * S_SPARSE;
        const float* sy = sx + S_SPARSE;
        const float* sz = sy + S_SPARSE;
        for (int j = threadIdx.x; j < S_SPARSE; j += THREADS)
            sp[j] = make_float4(sx[j], sy[j], sz[j], 0.0f);
    }
    __syncthreads();

    // ---- query point (fp64) ----
    const float* xb = xyz + (size_t)b * 3 * N;
    const double qx = (double)xb[pt];
    const double qy = (double)xb[N + pt];
    const double qz = (double)xb[2 * N + pt];

    // ---- scan my S/NSPLIT interleaved sparse points, keep sorted top-3 ----
    double b0 = 1e300, b1 = 1e300, b2 = 1e300;
    int    j0 = 0,     j1 = 0,     j2 = 0;

    #pragma unroll 4
    for (int i = 0; i < S_SPARSE / NSPLIT; ++i) {
        const int    j  = (i << 2) | split;
        const float4 p  = sp[j];
        const double dx = qx - (double)p.x;
        const double dy = qy - (double)p.y;
        const double dz = qz - (double)p.z;
        const double d2 = dx * dx + dy * dy + dz * dz;
        if (d2 < b2) {
            if (d2 < b1) {
                b2 = b1; j2 = j1;
                if (d2 < b0) { b1 = b0; j1 = j0; b0 = d2; j0 = j; }
                else         { b1 = d2; j1 = j; }
            } else {
                b2 = d2; j2 = j;
            }
        }
    }

    md[lp][split][0] = b0; md[lp][split][1] = b1; md[lp][split][2] = b2;
    mi[lp][split][0] = j0; mi[lp][split][1] = j1; mi[lp][split][2] = j2;
    __syncthreads();

    // ---- merge the 4 partial top-3 lists, compute weights + output ----
    if (split == 0) {
        double e0 = 1e300, e1 = 1e300, e2 = 1e300;
        int    k0 = 0,     k1 = 0,     k2 = 0;
        #pragma unroll
        for (int t = 0; t < NSPLIT; ++t) {
            #pragma unroll
            for (int k = 0; k < 3; ++k) {
                const double d = md[lp][t][k];
                const int    j = mi[lp][t][k];
                if (d < e2) {
                    if (d < e1) {
                        e2 = e1; k2 = k1;
                        if (d < e0) { e1 = e0; k1 = k0; e0 = d; k0 = j; }
                        else        { e1 = d;  k1 = j; }
                    } else {
                        e2 = d; k2 = j;
                    }
                }
            }
        }

        const int jj0 = k0, jj1 = k1, jj2 = k2;
        double inv0, inv1, inv2;
        {
            const float4 p = sp[jj0];
            const double dx = qx - (double)p.x, dy = qy - (double)p.y, dz = qz - (double)p.z;
            double dist = sqrt(dx * dx + dy * dy + dz * dz);
            dist = dist > 1e-10 ? dist : 1e-10;
            inv0 = 1.0 / dist;
        }
        {
            const float4 p = sp[jj1];
            const double dx = qx - (double)p.x, dy = qy - (double)p.y, dz = qz - (double)p.z;
            double dist = sqrt(dx * dx + dy * dy + dz * dz);
            dist = dist > 1e-10 ? dist : 1e-10;
            inv1 = 1.0 / dist;
        }
        {
            const float4 p = sp[jj2];
            const double dx = qx - (double)p.x, dy = qy - (double)p.y, dz = qz - (double)p.z;
            double dist = sqrt(dx * dx + dy * dy + dz * dz);
            dist = dist > 1e-10 ? dist : 1e-10;
            inv2 = 1.0 / dist;
        }
        const double wsum = inv0 + inv1 + inv2;

        const float* fb = sflow + (size_t)b * 3 * S_SPARSE;
        float*       ob = out   + (size_t)b * 3 * N;
        #pragma unroll
        for (int c = 0; c < 3; ++c) {
            const float* fc = fb + c * S_SPARSE;
            const double o =
                (inv0 * (double)fc[jj0] +
                 inv1 * (double)fc[jj1] +
                 inv2 * (double)fc[jj2]) / wsum;
            ob[c * N + pt] = (float)o;
        }
    }
}

extern "C" void kernel_launch(void* const* d_in, const int* in_sizes, int n_in,
                              void* d_out, int out_size, void* d_ws, size_t ws_size,
                              hipStream_t stream)
{
    const float* xyz  = (const float*)d_in[0];
    const float* sxyz = (const float*)d_in[1];
    const float* sflw = (const float*)d_in[2];
    float*       out  = (float*)d_out;

    const int B = 2;
    const int N = in_sizes[0] / (3 * B);   // 16384

    dim3 grid(N / PPB, B);
    upsample_knn3<<<grid, THREADS, 0, stream>>>(xyz, sxyz, sflw, out, N);
}

// Round 2
// 68.303 us; speedup vs baseline: 1.7431x; 1.7431x over previous
//
#include <hip/hip_runtime.h>

// 3-NN IDW upsampling, round 2.
// fp32 packed-key scan (key = d2 bits with low 12 mantissa bits replaced by j),
// branchless u32 sorted-bubble top-5 per thread-split, Q=4 query tiling,
// per-point merge of 16 splits -> top-8 candidates, exact-f64 re-rank + weights
// (identical arithmetic to the round-1 kernel that passed at absmax 3.9e-3).

constexpr int S_SPARSE = 4096;
constexpr int NSPLIT   = 16;                 // splits of S per point
constexpr int Q        = 4;                  // queries (dense points) per thread
constexpr int THREADS  = 256;
constexpr int PPB      = THREADS * Q / NSPLIT;   // 64 points per block
constexpr int NITER    = S_SPARSE / NSPLIT;      // 256 scan iters per thread
constexpr int K        = 5;                  // per-split top-K kept
constexpr int KM       = 8;                  // merged candidates kept for f64 re-rank
constexpr int KROW     = NSPLIT * K + 1;     // 81 (pad to break bank stride)

__global__ __launch_bounds__(THREADS)
void upsample_knn3(const float* __restrict__ xyz,
                   const float* __restrict__ sxyz,
                   const float* __restrict__ sflow,
                   float* __restrict__ out,
                   int N)
{
    // 64 KiB: float4 sparse coords during scan; aliased as the key-exchange
    // buffer afterwards (merge re-reads coords from global/L2 instead).
    __shared__ __align__(16) unsigned char smem_raw[S_SPARSE * sizeof(float4)];
    float4*   sp   = reinterpret_cast<float4*>(smem_raw);
    unsigned* kbuf = reinterpret_cast<unsigned*>(smem_raw);

    const int b = blockIdx.y;
    const int t = threadIdx.x;
    const int g = t >> 4;       // point-group 0..15
    const int s = t & 15;       // split 0..15

    // ---- stage sparse coords (SoA global -> AoS float4 LDS) ----
    const float* sx = sxyz + (size_t)b * 3 * S_SPARSE;
    const float* sy = sx + S_SPARSE;
    const float* sz = sy + S_SPARSE;
    #pragma unroll
    for (int it = 0; it < S_SPARSE / THREADS; ++it) {
        const int j = t + it * THREADS;
        sp[j] = make_float4(sx[j], sy[j], sz[j], 0.0f);
    }

    // ---- my 4 query points (fp32 for the scan) ----
    const float* xb = xyz + (size_t)b * 3 * N;
    const int p0 = blockIdx.x * PPB + g * Q;
    float qx[Q], qy[Q], qz[Q];
    #pragma unroll
    for (int q = 0; q < Q; ++q) {
        qx[q] = xb[p0 + q];
        qy[q] = xb[N + p0 + q];
        qz[q] = xb[2 * N + p0 + q];
    }
    __syncthreads();

    // ---- scan: branchless sorted top-5 packed keys per query ----
    unsigned key[Q][K];
    #pragma unroll
    for (int q = 0; q < Q; ++q)
        #pragma unroll
        for (int k = 0; k < K; ++k) key[q][k] = 0xFFFFFFFFu;

    #pragma unroll 4
    for (int i = 0; i < NITER; ++i) {
        const int    j = (i << 4) | s;          // 12-bit sparse index
        const float4 p = sp[j];
        #pragma unroll
        for (int q = 0; q < Q; ++q) {
            const float dx = qx[q] - p.x;
            const float dy = qy[q] - p.y;
            const float dz = qz[q] - p.z;
            const float d2 = dx * dx + dy * dy + dz * dz;   // >= 0, bits u32-monotone
            unsigned c = (__float_as_uint(d2) & 0xFFFFF000u) | (unsigned)j;
            #pragma unroll
            for (int k = 0; k < K - 1; ++k) {
                const unsigned old = key[q][k];
                const unsigned lo  = min(old, c);
                const unsigned hi  = max(old, c);
                key[q][k] = lo;
                c = hi;
            }
            key[q][K - 1] = min(key[q][K - 1], c);
        }
    }

    // ---- publish per-split lists (alias over sp: all sp reads are done) ----
    __syncthreads();
    #pragma unroll
    for (int q = 0; q < Q; ++q)
        #pragma unroll
        for (int k = 0; k < K; ++k)
            kbuf[(g * Q + q) * KROW + (s * K + k)] = key[q][k];
    __syncthreads();

    // ---- per-point merge (wave 0): top-8 of 80 keys, then f64 re-rank ----
    if (t < PPB) {
        unsigned bk[KM];
        #pragma unroll
        for (int k = 0; k < KM; ++k) bk[k] = 0xFFFFFFFFu;

        for (int c = 0; c < NSPLIT * K; ++c) {
            unsigned kk = kbuf[t * KROW + c];
            #pragma unroll
            for (int k = 0; k < KM - 1; ++k) {
                const unsigned old = bk[k];
                const unsigned lo  = min(old, kk);
                const unsigned hi  = max(old, kk);
                bk[k] = lo;
                kk = hi;
            }
            bk[KM - 1] = min(bk[KM - 1], kk);
        }

        // exact-f64 re-rank of the 8 candidates (matches round-1 ordering)
        const int pt = blockIdx.x * PPB + t;
        const double qxd = (double)xb[pt];
        const double qyd = (double)xb[N + pt];
        const double qzd = (double)xb[2 * N + pt];

        double e0 = 1e300, e1 = 1e300, e2 = 1e300;
        int    j0 = 0,     j1 = 0,     j2 = 0;
        #pragma unroll
        for (int c = 0; c < KM; ++c) {
            const int    j  = (int)(bk[c] & 0xFFFu);
            const double dx = qxd - (double)sx[j];
            const double dy = qyd - (double)sy[j];
            const double dz = qzd - (double)sz[j];
            const double d2 = dx * dx + dy * dy + dz * dz;
            if (d2 < e2) {
                if (d2 < e1) {
                    e2 = e1; j2 = j1;
                    if (d2 < e0) { e1 = e0; j1 = j0; e0 = d2; j0 = j; }
                    else         { e1 = d2; j1 = j; }
                } else {
                    e2 = d2; j2 = j;
                }
            }
        }

        // inverse-distance weights in f64 (identical to round-1)
        double dist0 = sqrt(e0); dist0 = dist0 > 1e-10 ? dist0 : 1e-10;
        double dist1 = sqrt(e1); dist1 = dist1 > 1e-10 ? dist1 : 1e-10;
        double dist2 = sqrt(e2); dist2 = dist2 > 1e-10 ? dist2 : 1e-10;
        const double inv0 = 1.0 / dist0;
        const double inv1 = 1.0 / dist1;
        const double inv2 = 1.0 / dist2;
        const double wsum = inv0 + inv1 + inv2;

        const float* fb = sflow + (size_t)b * 3 * S_SPARSE;
        float*       ob = out   + (size_t)b * 3 * N;
        #pragma unroll
        for (int c = 0; c < 3; ++c) {
            const float* fc = fb + c * S_SPARSE;
            const double o =
                (inv0 * (double)fc[j0] +
                 inv1 * (double)fc[j1] +
                 inv2 * (double)fc[j2]) / wsum;
            ob[c * N + pt] = (float)o;
        }
    }
}

extern "C" void kernel_launch(void* const* d_in, const int* in_sizes, int n_in,
                              void* d_out, int out_size, void* d_ws, size_t ws_size,
                              hipStream_t stream)
{
    const float* xyz  = (const float*)d_in[0];
    const float* sxyz = (const float*)d_in[1];
    const float* sflw = (const float*)d_in[2];
    float*       out  = (float*)d_out;

    const int B = 2;
    const int N = in_sizes[0] / (3 * B);   // 16384

    dim3 grid(N / PPB, B);
    upsample_knn3<<<grid, THREADS, 0, stream>>>(xyz, sxyz, sflw, out, N);
}

// Round 3
// 47.802 us; speedup vs baseline: 2.4907x; 1.4289x over previous
//
#include <hip/hip_runtime.h>

// 3-NN IDW upsampling, round 3.
// fp32 packed-key scan (key = d2 bits, low 12 mantissa bits replaced by j),
// med3-based sorted-insert (1 VALU op per list level), Q=8 query tiling,
// NSPLIT=32, per-split top-4 -> 2-stage merge -> top-8 -> exact-f64 re-rank
// + f64 weights (identical epilogue arithmetic to rounds 1-2, absmax 3.9e-3).

constexpr int S_SPARSE = 4096;
constexpr int NSPLIT   = 32;                 // splits of S per point
constexpr int Q        = 8;                  // queries per thread
constexpr int THREADS  = 256;
constexpr int PPB      = THREADS * Q / NSPLIT;   // 64 points per block
constexpr int NITER    = S_SPARSE / NSPLIT;      // 128 scan iters per thread
constexpr int K        = 4;                  // per-split top-K kept
constexpr int KM       = 8;                  // merged candidates for f64 re-rank
constexpr int KROW     = NSPLIT * K + 4;     // 132 (pad breaks bank stride)
constexpr int KBUF2_OFF = PPB * KROW * 4;    // 33792 B, 16B-aligned

__device__ __forceinline__ unsigned med3u(unsigned a, unsigned b, unsigned c) {
    unsigned d;
    asm("v_med3_u32 %0, %1, %2, %3" : "=v"(d) : "v"(a), "v"(b), "v"(c));
    return d;
}

__global__ __launch_bounds__(THREADS)
void upsample_knn3(const float* __restrict__ xyz,
                   const float* __restrict__ sxyz,
                   const float* __restrict__ sflow,
                   float* __restrict__ out,
                   int N)
{
    // 64 KiB: float4 sparse coords during scan; aliased as key-exchange after.
    __shared__ __align__(16) unsigned char smem_raw[S_SPARSE * sizeof(float4)];
    float4*   sp    = reinterpret_cast<float4*>(smem_raw);
    unsigned* kbuf  = reinterpret_cast<unsigned*>(smem_raw);
    uint4*    kbuf2 = reinterpret_cast<uint4*>(smem_raw + KBUF2_OFF);

    const int b = blockIdx.y;
    const int t = threadIdx.x;
    const int g = t >> 5;        // point-group 0..7 (8 queries each)
    const int s = t & 31;        // split 0..31

    // ---- stage sparse coords, vectorized (float4 per SoA plane) ----
    const float* sx = sxyz + (size_t)b * 3 * S_SPARSE;
    const float* sy = sx + S_SPARSE;
    const float* sz = sy + S_SPARSE;
    #pragma unroll
    for (int it = 0; it < S_SPARSE / (THREADS * 4); ++it) {
        const int j0 = (t + it * THREADS) * 4;
        const float4 vx = *reinterpret_cast<const float4*>(sx + j0);
        const float4 vy = *reinterpret_cast<const float4*>(sy + j0);
        const float4 vz = *reinterpret_cast<const float4*>(sz + j0);
        sp[j0 + 0] = make_float4(vx.x, vy.x, vz.x, 0.0f);
        sp[j0 + 1] = make_float4(vx.y, vy.y, vz.y, 0.0f);
        sp[j0 + 2] = make_float4(vx.z, vy.z, vz.z, 0.0f);
        sp[j0 + 3] = make_float4(vx.w, vy.w, vz.w, 0.0f);
    }

    // ---- my 8 query points (fp32 scan coords) ----
    const float* xb = xyz + (size_t)b * 3 * N;
    const int p0 = blockIdx.x * PPB + g * Q;
    float qx[Q], qy[Q], qz[Q];
    {
        const float4 x0 = *reinterpret_cast<const float4*>(xb + p0);
        const float4 x1 = *reinterpret_cast<const float4*>(xb + p0 + 4);
        const float4 y0 = *reinterpret_cast<const float4*>(xb + N + p0);
        const float4 y1 = *reinterpret_cast<const float4*>(xb + N + p0 + 4);
        const float4 z0 = *reinterpret_cast<const float4*>(xb + 2 * N + p0);
        const float4 z1 = *reinterpret_cast<const float4*>(xb + 2 * N + p0 + 4);
        qx[0]=x0.x; qx[1]=x0.y; qx[2]=x0.z; qx[3]=x0.w; qx[4]=x1.x; qx[5]=x1.y; qx[6]=x1.z; qx[7]=x1.w;
        qy[0]=y0.x; qy[1]=y0.y; qy[2]=y0.z; qy[3]=y0.w; qy[4]=y1.x; qy[5]=y1.y; qy[6]=y1.z; qy[7]=y1.w;
        qz[0]=z0.x; qz[1]=z0.y; qz[2]=z0.z; qz[3]=z0.w; qz[4]=z1.x; qz[5]=z1.y; qz[6]=z1.z; qz[7]=z1.w;
    }
    __syncthreads();

    // ---- scan: med3 sorted top-4 packed keys per query ----
    unsigned k0[Q], k1[Q], k2[Q], k3[Q];
    #pragma unroll
    for (int q = 0; q < Q; ++q) { k0[q]=0xFFFFFFFFu; k1[q]=0xFFFFFFFFu; k2[q]=0xFFFFFFFFu; k3[q]=0xFFFFFFFFu; }

    #pragma unroll 2
    for (int i = 0; i < NITER; ++i) {
        const int    j = (i << 5) | s;          // 12-bit sparse index
        const float4 p = sp[j];
        #pragma unroll
        for (int q = 0; q < Q; ++q) {
            const float dx = qx[q] - p.x;
            const float dy = qy[q] - p.y;
            const float dz = qz[q] - p.z;
            const float d2 = dx * dx + dy * dy + dz * dz;   // >=0, u32-monotone bits
            const unsigned c = (__float_as_uint(d2) & 0xFFFFF000u) | (unsigned)j;
            // sorted insert, 4 ops (old values read before overwrite)
            k3[q] = med3u(k2[q], k3[q], c);
            k2[q] = med3u(k1[q], k2[q], c);
            k1[q] = med3u(k0[q], k1[q], c);
            k0[q] = min(k0[q], c);
        }
    }

    // ---- publish per-split sorted-4 lists (alias over sp) ----
    __syncthreads();
    #pragma unroll
    for (int q = 0; q < Q; ++q) {
        const int lp = g * Q + q;               // local point 0..63
        *reinterpret_cast<uint4*>(&kbuf[lp * KROW + s * K]) =
            make_uint4(k0[q], k1[q], k2[q], k3[q]);
    }
    __syncthreads();

    // ---- merge stage A: 4 threads/point, each folds 32 candidates -> top-4 ----
    {
        const int lp = t >> 2;
        const int qd = t & 3;
        unsigned m0 = 0xFFFFFFFFu, m1 = 0xFFFFFFFFu, m2 = 0xFFFFFFFFu, m3 = 0xFFFFFFFFu;
        const unsigned* rowp = kbuf + lp * KROW + qd * 32;
        #pragma unroll
        for (int c = 0; c < 32; c += 4) {
            const uint4 v = *reinterpret_cast<const uint4*>(rowp + c);
            #pragma unroll
            for (int e = 0; e < 4; ++e) {
                const unsigned cc = (&v.x)[e];
                m3 = med3u(m2, m3, cc);
                m2 = med3u(m1, m2, cc);
                m1 = med3u(m0, m1, cc);
                m0 = min(m0, cc);
            }
        }
        kbuf2[lp * 4 + qd] = make_uint4(m0, m1, m2, m3);   // disjoint region, no barrier needed before write
    }
    __syncthreads();

    // ---- merge stage B + exact-f64 re-rank + weights + output (t < 64) ----
    if (t < PPB) {
        unsigned bk[KM];
        #pragma unroll
        for (int k = 0; k < KM; ++k) bk[k] = 0xFFFFFFFFu;
        #pragma unroll
        for (int c4 = 0; c4 < 4; ++c4) {
            const uint4 v = kbuf2[t * 4 + c4];
            #pragma unroll
            for (int e = 0; e < 4; ++e) {
                const unsigned cc = (&v.x)[e];
                bk[7] = med3u(bk[6], bk[7], cc);
                bk[6] = med3u(bk[5], bk[6], cc);
                bk[5] = med3u(bk[4], bk[5], cc);
                bk[4] = med3u(bk[3], bk[4], cc);
                bk[3] = med3u(bk[2], bk[3], cc);
                bk[2] = med3u(bk[1], bk[2], cc);
                bk[1] = med3u(bk[0], bk[1], cc);
                bk[0] = min(bk[0], cc);
            }
        }

        // exact-f64 re-rank of the 8 candidates (identical to rounds 1-2)
        const int pt = blockIdx.x * PPB + t;
        const double qxd = (double)xb[pt];
        const double qyd = (double)xb[N + pt];
        const double qzd = (double)xb[2 * N + pt];

        double e0 = 1e300, e1 = 1e300, e2 = 1e300;
        int    j0 = 0,     j1 = 0,     j2 = 0;
        #pragma unroll
        for (int c = 0; c < KM; ++c) {
            const int    j  = (int)(bk[c] & 0xFFFu);
            const double dx = qxd - (double)sx[j];
            const double dy = qyd - (double)sy[j];
            const double dz = qzd - (double)sz[j];
            const double d2 = dx * dx + dy * dy + dz * dz;
            if (d2 < e2) {
                if (d2 < e1) {
                    e2 = e1; j2 = j1;
                    if (d2 < e0) { e1 = e0; j1 = j0; e0 = d2; j0 = j; }
                    else         { e1 = d2; j1 = j; }
                } else {
                    e2 = d2; j2 = j;
                }
            }
        }

        double dist0 = sqrt(e0); dist0 = dist0 > 1e-10 ? dist0 : 1e-10;
        double dist1 = sqrt(e1); dist1 = dist1 > 1e-10 ? dist1 : 1e-10;
        double dist2 = sqrt(e2); dist2 = dist2 > 1e-10 ? dist2 : 1e-10;
        const double inv0 = 1.0 / dist0;
        const double inv1 = 1.0 / dist1;
        const double inv2 = 1.0 / dist2;
        const double wsum = inv0 + inv1 + inv2;

        const float* fb = sflow + (size_t)b * 3 * S_SPARSE;
        float*       ob = out   + (size_t)b * 3 * N;
        #pragma unroll
        for (int c = 0; c < 3; ++c) {
            const float* fc = fb + c * S_SPARSE;
            const double o =
                (inv0 * (double)fc[j0] +
                 inv1 * (double)fc[j1] +
                 inv2 * (double)fc[j2]) / wsum;
            ob[c * N + pt] = (float)o;
        }
    }
}

extern "C" void kernel_launch(void* const* d_in, const int* in_sizes, int n_in,
                              void* d_out, int out_size, void* d_ws, size_t ws_size,
                              hipStream_t stream)
{
    const float* xyz  = (const float*)d_in[0];
    const float* sxyz = (const float*)d_in[1];
    const float* sflw = (const float*)d_in[2];
    float*       out  = (float*)d_out;

    const int B = 2;
    const int N = in_sizes[0] / (3 * B);   // 16384

    dim3 grid(N / PPB, B);
    upsample_knn3<<<grid, THREADS, 0, stream>>>(xyz, sxyz, sflw, out, N);
}

// Round 4
// 44.222 us; speedup vs baseline: 2.6923x; 1.0810x over previous
//
#include <hip/hip_runtime.h>

// 3-NN IDW upsampling, round 4.
// Changes vs round 3: PPB 64->32 (grid 1024 blocks), LDS 64KB->48KB SoA planes
// (-> 3 blocks/CU = 12 waves/CU resident), explicit 1-deep LDS prefetch,
// per-split top-3 (2 med3 + 1 min insert). fp32 d2 expression, f64 re-rank and
// f64 weight epilogue bit-identical to round 3 (absmax 0.00390625).

constexpr int S_SPARSE = 4096;
constexpr int NSPLIT   = 64;                 // splits of S per point
constexpr int Q        = 8;                  // queries per thread
constexpr int THREADS  = 256;
constexpr int PPB      = THREADS * Q / NSPLIT;   // 32 points per block
constexpr int NITER    = S_SPARSE / NSPLIT;      // 64 scan iters per thread
constexpr int K        = 3;                  // per-split top-K kept
constexpr int KA       = 5;                  // stage-A top-K per 24-key chunk
constexpr int KM       = 8;                  // final candidates for f64 re-rank
constexpr int KROW     = NSPLIT * K + 8;     // 200 dwords (pad breaks stride)
constexpr int KBUF2_OFF_DW = PPB * KROW;     // 6400 dwords = 25600 B
constexpr int SLIN_PAD = 64;                 // prefetch overrun guard

__device__ __forceinline__ unsigned med3u(unsigned a, unsigned b, unsigned c) {
    unsigned d;
    asm("v_med3_u32 %0, %1, %2, %3" : "=v"(d) : "v"(a), "v"(b), "v"(c));
    return d;
}

__global__ __launch_bounds__(THREADS)
void upsample_knn3(const float* __restrict__ xyz,
                   const float* __restrict__ sxyz,
                   const float* __restrict__ sflow,
                   float* __restrict__ out,
                   int N)
{
    // 49.4 KiB: 3 SoA coordinate planes (+ pad) during scan; aliased as the
    // key-exchange buffers afterwards (epilogue re-reads coords from L2).
    __shared__ __align__(16) unsigned char smem_raw[(3 * S_SPARSE + SLIN_PAD) * 4];
    float*    slin = reinterpret_cast<float*>(smem_raw);
    unsigned* kbuf = reinterpret_cast<unsigned*>(smem_raw);

    const int b = blockIdx.y;
    const int t = threadIdx.x;
    const int g = t >> 6;        // point-group 0..3 (8 queries each)
    const int s = t & 63;        // split 0..63

    // ---- stage sparse coords: 3 planes are contiguous in global -> linear copy
    const float* sx = sxyz + (size_t)b * 3 * S_SPARSE;
    const float* sy = sx + S_SPARSE;
    const float* sz = sy + S_SPARSE;
    #pragma unroll
    for (int it = 0; it < 3 * S_SPARSE / (THREADS * 4); ++it) {   // 12 iters
        const int j0 = (t + it * THREADS) * 4;
        *reinterpret_cast<float4*>(slin + j0) =
            *reinterpret_cast<const float4*>(sx + j0);
    }

    // ---- my 8 query points (fp32 scan coords) ----
    const float* xb = xyz + (size_t)b * 3 * N;
    const int p0 = blockIdx.x * PPB + g * Q;
    float qx[Q], qy[Q], qz[Q];
    {
        const float4 x0 = *reinterpret_cast<const float4*>(xb + p0);
        const float4 x1 = *reinterpret_cast<const float4*>(xb + p0 + 4);
        const float4 y0 = *reinterpret_cast<const float4*>(xb + N + p0);
        const float4 y1 = *reinterpret_cast<const float4*>(xb + N + p0 + 4);
        const float4 z0 = *reinterpret_cast<const float4*>(xb + 2 * N + p0);
        const float4 z1 = *reinterpret_cast<const float4*>(xb + 2 * N + p0 + 4);
        qx[0]=x0.x; qx[1]=x0.y; qx[2]=x0.z; qx[3]=x0.w; qx[4]=x1.x; qx[5]=x1.y; qx[6]=x1.z; qx[7]=x1.w;
        qy[0]=y0.x; qy[1]=y0.y; qy[2]=y0.z; qy[3]=y0.w; qy[4]=y1.x; qy[5]=y1.y; qy[6]=y1.z; qy[7]=y1.w;
        qz[0]=z0.x; qz[1]=z0.y; qz[2]=z0.z; qz[3]=z0.w; qz[4]=z1.x; qz[5]=z1.y; qz[6]=z1.z; qz[7]=z1.w;
    }
    __syncthreads();

    // ---- scan: med3 sorted top-3 packed keys per query, 1-deep LDS prefetch
    unsigned k0[Q], k1[Q], k2[Q];
    #pragma unroll
    for (int q = 0; q < Q; ++q) { k0[q]=0xFFFFFFFFu; k1[q]=0xFFFFFFFFu; k2[q]=0xFFFFFFFFu; }

    float px = slin[s], py = slin[s + S_SPARSE], pz = slin[s + 2 * S_SPARSE];

    #pragma unroll 4
    for (int i = 0; i < NITER; ++i) {
        const float cx = px, cy = py, cz = pz;
        const int   cj = (i << 6) | s;
        const int   jn = cj + 64;               // overruns into pad at i=63: unused
        px = slin[jn];
        py = slin[jn + S_SPARSE];
        pz = slin[jn + 2 * S_SPARSE];
        #pragma unroll
        for (int q = 0; q < Q; ++q) {
            const float dx = qx[q] - cx;
            const float dy = qy[q] - cy;
            const float dz = qz[q] - cz;
            const float d2 = dx * dx + dy * dy + dz * dz;   // >=0, u32-monotone bits
            const unsigned c = (__float_as_uint(d2) & 0xFFFFF000u) | (unsigned)cj;
            k2[q] = med3u(k1[q], k2[q], c);
            k1[q] = med3u(k0[q], k1[q], c);
            k0[q] = min(k0[q], c);
        }
    }

    // ---- publish per-split sorted-3 lists (alias over slin) ----
    __syncthreads();
    #pragma unroll
    for (int q = 0; q < Q; ++q) {
        const int base = (g * Q + q) * KROW + s * K;   // bank = 3s mod 32: 2-way, free
        kbuf[base + 0] = k0[q];
        kbuf[base + 1] = k1[q];
        kbuf[base + 2] = k2[q];
    }
    __syncthreads();

    // ---- merge stage A: 8 threads/point, each folds 24 keys -> top-5 ----
    {
        const int lp = t >> 3;                  // local point 0..31
        const int ch = t & 7;                   // chunk 0..7
        unsigned m0=0xFFFFFFFFu, m1=0xFFFFFFFFu, m2=0xFFFFFFFFu, m3=0xFFFFFFFFu, m4=0xFFFFFFFFu;
        const unsigned* rowp = kbuf + lp * KROW + ch * 24;
        #pragma unroll
        for (int c = 0; c < 24; ++c) {
            const unsigned cc = rowp[c];
            m4 = med3u(m3, m4, cc);
            m3 = med3u(m2, m3, cc);
            m2 = med3u(m1, m2, cc);
            m1 = med3u(m0, m1, cc);
            m0 = min(m0, cc);
        }
        unsigned* o = kbuf + KBUF2_OFF_DW + (lp * 8 + ch) * KA;   // disjoint region
        o[0]=m0; o[1]=m1; o[2]=m2; o[3]=m3; o[4]=m4;
    }
    __syncthreads();

    // ---- merge stage B + exact-f64 re-rank + weights + output (t < 32) ----
    if (t < PPB) {
        unsigned bk[KM];
        #pragma unroll
        for (int k = 0; k < KM; ++k) bk[k] = 0xFFFFFFFFu;
        const unsigned* inp = kbuf + KBUF2_OFF_DW + t * 8 * KA;
        #pragma unroll
        for (int c = 0; c < 8 * KA; ++c) {
            const unsigned cc = inp[c];
            bk[7] = med3u(bk[6], bk[7], cc);
            bk[6] = med3u(bk[5], bk[6], cc);
            bk[5] = med3u(bk[4], bk[5], cc);
            bk[4] = med3u(bk[3], bk[4], cc);
            bk[3] = med3u(bk[2], bk[3], cc);
            bk[2] = med3u(bk[1], bk[2], cc);
            bk[1] = med3u(bk[0], bk[1], cc);
            bk[0] = min(bk[0], cc);
        }

        // exact-f64 re-rank of the 8 candidates (identical to rounds 1-3)
        const int pt = blockIdx.x * PPB + t;
        const double qxd = (double)xb[pt];
        const double qyd = (double)xb[N + pt];
        const double qzd = (double)xb[2 * N + pt];

        double e0 = 1e300, e1 = 1e300, e2 = 1e300;
        int    j0 = 0,     j1 = 0,     j2 = 0;
        #pragma unroll
        for (int c = 0; c < KM; ++c) {
            const int    j  = (int)(bk[c] & 0xFFFu);
            const double dx = qxd - (double)sx[j];
            const double dy = qyd - (double)sy[j];
            const double dz = qzd - (double)sz[j];
            const double d2 = dx * dx + dy * dy + dz * dz;
            if (d2 < e2) {
                if (d2 < e1) {
                    e2 = e1; j2 = j1;
                    if (d2 < e0) { e1 = e0; j1 = j0; e0 = d2; j0 = j; }
                    else         { e1 = d2; j1 = j; }
                } else {
                    e2 = d2; j2 = j;
                }
            }
        }

        double dist0 = sqrt(e0); dist0 = dist0 > 1e-10 ? dist0 : 1e-10;
        double dist1 = sqrt(e1); dist1 = dist1 > 1e-10 ? dist1 : 1e-10;
        double dist2 = sqrt(e2); dist2 = dist2 > 1e-10 ? dist2 : 1e-10;
        const double inv0 = 1.0 / dist0;
        const double inv1 = 1.0 / dist1;
        const double inv2 = 1.0 / dist2;
        const double wsum = inv0 + inv1 + inv2;

        const float* fb = sflow + (size_t)b * 3 * S_SPARSE;
        float*       ob = out   + (size_t)b * 3 * N;
        #pragma unroll
        for (int c = 0; c < 3; ++c) {
            const float* fc = fb + c * S_SPARSE;
            const double o =
                (inv0 * (double)fc[j0] +
                 inv1 * (double)fc[j1] +
                 inv2 * (double)fc[j2]) / wsum;
            ob[c * N + pt] = (float)o;
        }
    }
}

extern "C" void kernel_launch(void* const* d_in, const int* in_sizes, int n_in,
                              void* d_out, int out_size, void* d_ws, size_t ws_size,
                              hipStream_t stream)
{
    const float* xyz  = (const float*)d_in[0];
    const float* sxyz = (const float*)d_in[1];
    const float* sflw = (const float*)d_in[2];
    float*       out  = (float*)d_out;

    const int B = 2;
    const int N = in_sizes[0] / (3 * B);   // 16384

    dim3 grid(N / PPB, B);
    upsample_knn3<<<grid, THREADS, 0, stream>>>(xyz, sxyz, sflw, out, N);
}